// Round 1
// baseline (994.970 us; speedup 1.0000x reference)
//
#include <hip/hip_runtime.h>

typedef __attribute__((ext_vector_type(4))) float f4v;
typedef __attribute__((ext_vector_type(8))) short s8v;
typedef __attribute__((ext_vector_type(4))) short s4v;

#define PITCH 72  // 72 shorts = 144 B row pitch: 16B-aligned, 4m%32 bank walk (2-way, free)

static __device__ __forceinline__ short f2bf(float f) {
    unsigned u = __builtin_bit_cast(unsigned, f);
    unsigned r = (u + 0x7FFFu + ((u >> 16) & 1u)) >> 16;  // RNE
    return (short)r;
}

// W[3][256][256] (k,f,o) fp32  ->  Wt[3][256][256] (k,o,f) bf16, via LDS tile transpose
__global__ void wt_transpose_kernel(const float* __restrict__ W, short* __restrict__ Wt) {
    __shared__ short t[64][65];
    int k  = blockIdx.x >> 4;
    int r  = blockIdx.x & 15;
    int f0 = (r >> 2) << 6;
    int o0 = (r & 3) << 6;
    const float* Wk  = W  + k * 65536;
    short*       Wtk = Wt + k * 65536;
    #pragma unroll
    for (int e = 0; e < 16; e++) {
        int idx = e * 256 + threadIdx.x;
        int f = idx >> 6, o = idx & 63;
        t[f][o] = f2bf(Wk[(f0 + f) * 256 + o0 + o]);
    }
    __syncthreads();
    #pragma unroll
    for (int e = 0; e < 16; e++) {
        int idx = e * 256 + threadIdx.x;
        int o = idx >> 6, f = idx & 63;
        Wtk[(o0 + o) * 256 + f0 + f] = t[f][o];
    }
}

// Fused: Y_k = A_k x (register aggregation, fp32) -> bf16 LDS -> MFMA vs Wt -> out + bias
__global__ __launch_bounds__(256, 2) void gconv_kernel(
        const float* __restrict__ x, const short* __restrict__ Wt,
        const float* __restrict__ adj, const float* __restrict__ bias,
        float* __restrict__ out) {
    __shared__ __align__(16) short Ys[272 * PITCH];  // 39168 B
    __shared__ __align__(16) short Ws[128 * PITCH];  // 18432 B

    const int bx   = blockIdx.x;
    const int nh   = (bx >> 3) & 1;              // N-half; pair (g,0)/(g,1) are 8 apart -> same XCD
    const int g    = (bx >> 4) * 8 + (bx & 7);   // batch group 0..1023 (16 batches each)
    const int tid  = threadIdx.x;
    const int bb   = tid >> 4;                   // local batch 0..15
    const int fq   = tid & 15;                   // f-quad within 64-chunk
    const int o0   = nh << 7;
    const int wave = tid >> 6;
    const int lane = tid & 63;
    const int mn   = lane & 15;                  // m (A) / n (B) within tile
    const int quad = lane >> 4;

    const float* xg = x   + (size_t)g * (272 * 256);
    float*       og = out + (size_t)g * (272 * 256);

    f4v acc[17][2];
    #pragma unroll
    for (int nt = 0; nt < 2; nt++) {
        float bv = bias[o0 + wave * 32 + nt * 16 + mn];
        #pragma unroll
        for (int mt = 0; mt < 17; mt++) acc[mt][nt] = (f4v){bv, bv, bv, bv};
    }

    for (int fc0 = 0; fc0 < 256; fc0 += 64) {
        f4v xq[17];
        #pragma unroll
        for (int j = 0; j < 17; j++)
            xq[j] = *(const f4v*)(xg + (bb * 17 + j) * 256 + fc0 + fq * 4);

        #pragma unroll
        for (int k = 0; k < 3; k++) {
            // ---- aggregation: Y_k rows for all 17 output joints, fp32 in regs ----
            #pragma unroll
            for (int i = 0; i < 17; i++) {
                f4v a = {0.f, 0.f, 0.f, 0.f};
                if (k == 0) {
                    a = adj[i * 17 + i] * xq[i];
                } else if (k == 1) {
                    #pragma unroll
                    for (int j = i + 1; j < 17; j++) a += adj[i * 17 + j] * xq[j];
                } else {
                    #pragma unroll
                    for (int j = 0; j < i; j++) a += adj[i * 17 + j] * xq[j];
                }
                s4v p;
                p.x = f2bf(a.x); p.y = f2bf(a.y); p.z = f2bf(a.z); p.w = f2bf(a.w);
                *(s4v*)(Ys + (bb * 17 + i) * PITCH + fq * 4) = p;
            }
            // ---- stage Wt[k][o0..o0+128][fc0..fc0+64] -> Ws (bf16, K-contiguous) ----
            const short* Wtk = Wt + k * 65536;
            #pragma unroll
            for (int e = 0; e < 4; e++) {
                int idx = e * 256 + tid;
                int c = idx >> 3, sg = idx & 7;
                *(s8v*)(Ws + c * PITCH + sg * 8) =
                    *(const s8v*)(Wtk + (o0 + c) * 256 + fc0 + sg * 8);
            }
            __syncthreads();
            // ---- MFMA: 17 M-tiles x 2 N-tiles x 2 K-slices ----
            #pragma unroll
            for (int ks = 0; ks < 2; ks++) {
                const int ko = ks * 32 + quad * 8;
                s8v bf0 = *(const s8v*)(Ws + (wave * 32 + mn) * PITCH + ko);
                s8v bf1 = *(const s8v*)(Ws + (wave * 32 + 16 + mn) * PITCH + ko);
                #pragma unroll
                for (int mt = 0; mt < 17; mt++) {
                    s8v af = *(const s8v*)(Ys + (mt * 16 + mn) * PITCH + ko);
                    acc[mt][0] = __builtin_amdgcn_mfma_f32_16x16x32_bf16(af, bf0, acc[mt][0], 0, 0, 0);
                    acc[mt][1] = __builtin_amdgcn_mfma_f32_16x16x32_bf16(af, bf1, acc[mt][1], 0, 0, 0);
                }
            }
            __syncthreads();
        }
    }

    // ---- epilogue: C/D layout col=lane&15, row=quad*4+reg (m89-verified) ----
    #pragma unroll
    for (int mt = 0; mt < 17; mt++) {
        #pragma unroll
        for (int nt = 0; nt < 2; nt++) {
            int o  = o0 + wave * 32 + nt * 16 + mn;
            int rb = mt * 16 + quad * 4;
            #pragma unroll
            for (int rg = 0; rg < 4; rg++)
                og[(rb + rg) * 256 + o] = acc[mt][nt][rg];
        }
    }
}

extern "C" void kernel_launch(void* const* d_in, const int* in_sizes, int n_in,
                              void* d_out, int out_size, void* d_ws, size_t ws_size,
                              hipStream_t stream) {
    const float* x    = (const float*)d_in[0];
    const float* W    = (const float*)d_in[1];
    const float* adj  = (const float*)d_in[2];
    const float* bias = (const float*)d_in[3];
    float* out = (float*)d_out;
    short* Wt  = (short*)d_ws;  // 3*256*256 bf16 = 393 KB

    hipLaunchKernelGGL(wt_transpose_kernel, dim3(48), dim3(256), 0, stream, W, Wt);
    hipLaunchKernelGGL(gconv_kernel, dim3(2048), dim3(256), 0, stream,
                       x, Wt, adj, bias, out);
}